// Round 7
// baseline (2885.134 us; speedup 1.0000x reference)
//
#include <hip/hip_runtime.h>

// R15: (a) revert k_d1a to R13 batch-32 (R14's batch-16 doubled d1_w re-fetch,
// +54us regression); (b) k_c2 weight path: force VMEM instead of SMEM.
// R14 post-mortem: k_c2 at 540us, VALUBusy 82.6%; FMA floor 299us. Theory:
// weight s_loads (SMEM, out-of-order) share lgkmcnt with ds_reads, forcing
// lgkmcnt(0) drains before each FMA group. Fix: opaque asm moves the weight
// base into VGPRs -> global_load_dwordx4 (vmcnt, L1-broadcast), lgkm queue
// is then pure in-order ds_read -> precise waits. Also removed the wv[16]
// temp array (direct float4-member FMAs, same value, same order).
// All FMA chains byte-identical to R13/R14 (PASSED, absmax 0.00390625).
// NUMERICS CONTRACT (do not violate): golden is faithful float32 numpy;
// border-degenerate bilinear pixels flip discontinuously on ~1e-6 theta
// changes. Every conv/dense output must keep its exact sequential chain
// ((ky,kx) for conv1, (ky,kx,ic) for conv2, panel-k for dense1).
//
// ---- workspace (bytes), ~175MB ----
// th   f32[128*6]            @ 0
// h1   f32[128*120]          @ 4096
// p1   f32 NHWC [128][126][126][14] @ 65536      (113,799,168 B)
// part f32[311][128][120]    @ 65536  (19,107,840 B; overlaps p1: p1 is dead
//                                      before k_d1a writes part)
// p2   f32[128][119072]      @ 113930240         (60,964,864 B)
#define TH_OFF   0ull
#define H1_OFF   4096ull
#define P1_OFF   65536ull
#define PART_OFF 65536ull
#define P2_OFF   113930240ull

// ======= conv1 5x5 (1->14) + bias + relu + maxpool2, tiled =======
// block: 16x16 pool outputs, 1 batch; p1 NHWC [126][126][14]
__global__ __launch_bounds__(256) void k_c1(const float* __restrict__ x,
        const float* __restrict__ w1, const float* __restrict__ b1,
        float* __restrict__ p1)
{
    __shared__ float s_in[36*36];
    __shared__ float s_w[350];
    __shared__ float s_b[14];
    const int b   = blockIdx.z;
    const int ty0 = blockIdx.y * 16, tx0 = blockIdx.x * 16;
    const int tid = threadIdx.x;
    for (int i = tid; i < 36*36; i += 256) {
        int r = i / 36, c = i % 36;
        int gy = 2*ty0 + r, gx = 2*tx0 + c;
        float v = 0.f;
        if (gy < 256 && gx < 256) v = x[(long)(b*256 + gy)*256 + gx];
        s_in[i] = v;
    }
    for (int i = tid; i < 350; i += 256) s_w[i] = w1[i];
    if (tid < 14) s_b[tid] = b1[tid];
    __syncthreads();

    const int py = tid >> 4, px = tid & 15;
    float a0[14], a1[14], a2[14], a3[14];
    #pragma unroll
    for (int c = 0; c < 14; ++c) { a0[c]=0.f; a1[c]=0.f; a2[c]=0.f; a3[c]=0.f; }
    const int iy = 2*py, ix = 2*px;
    // chain order per accumulator: (ky,kx) sequential == R7
    #pragma unroll
    for (int ky = 0; ky < 5; ++ky) {
      #pragma unroll
      for (int kx = 0; kx < 5; ++kx) {
        float wv[14];
        #pragma unroll
        for (int c = 0; c < 14; ++c) wv[c] = s_w[(ky*5+kx)*14 + c];
        const float* ip = &s_in[(iy+ky)*36 + ix + kx];
        float v00 = ip[0],  v01 = ip[1];
        float v10 = ip[36], v11 = ip[37];
        #pragma unroll
        for (int c = 0; c < 14; ++c) {
            a0[c] = fmaf(v00, wv[c], a0[c]);
            a1[c] = fmaf(v01, wv[c], a1[c]);
            a2[c] = fmaf(v10, wv[c], a2[c]);
            a3[c] = fmaf(v11, wv[c], a3[c]);
        }
      }
    }
    const int oy = ty0 + py, ox = tx0 + px;
    if (oy < 126 && ox < 126) {
        float* op = &p1[((long)(b*126 + oy)*126 + ox)*14];
        #pragma unroll
        for (int c = 0; c < 14; ++c) {
            float bb = s_b[c];
            // R7 pool order: (0,0),(0,1),(1,0),(1,1)
            float m = fmaxf(__fadd_rn(a0[c], bb), 0.f);
            m = fmaxf(m, fmaxf(__fadd_rn(a1[c], bb), 0.f));
            m = fmaxf(m, fmaxf(__fadd_rn(a2[c], bb), 0.f));
            m = fmaxf(m, fmaxf(__fadd_rn(a3[c], bb), 0.f));
            op[c] = m;
        }
    }
}

// ======= conv2 5x5 (14->32) + bias + relu + maxpool2 (v6) =======
// block: 256 thr = 128 pos (8 conv rows x 16 col-pairs) x 2 oc-groups(16).
// LDS: s_in[12][14][38] = 25,536 B -> 6 blocks/CU; 8192 blocks.
// Weights: VMEM path (opaque-asm VGPR base) -> global_load_dwordx4, L1/L2
// broadcast hits, vmcnt-counted; lgkm queue left to in-order ds_reads.
// s_in layout [r][ic][cc pad 38]: conflict-free ds_read_b64 column pairs.
// Per-output FMA chain (ky,kx,ic) sequential, accL[c];accR[c] for c=0..15
// == R13's wv[c] loop order exactly. Pool via shfl_xor(16); bit-exact.
#define FMA2(WC, ACCI)                                              \
      accL[ACCI] = fmaf(vl, (WC), accL[ACCI]);                      \
      accR[ACCI] = fmaf(vr, (WC), accR[ACCI]);

#define C2_BLOCK(KX, VL, VR)                                        \
  { _Pragma("unroll")                                               \
    for (int ic = 0; ic < 14; ++ic) {                               \
      const float* wp = wb + ((ky*5 + (KX))*14 + ic)*32;            \
      float4 wA = *reinterpret_cast<const float4*>(wp);             \
      float4 wB = *reinterpret_cast<const float4*>(wp + 4);         \
      float4 wC = *reinterpret_cast<const float4*>(wp + 8);         \
      float4 wD = *reinterpret_cast<const float4*>(wp + 12);        \
      float vl = (VL), vr = (VR);                                   \
      FMA2(wA.x, 0)  FMA2(wA.y, 1)  FMA2(wA.z, 2)  FMA2(wA.w, 3)   \
      FMA2(wB.x, 4)  FMA2(wB.y, 5)  FMA2(wB.z, 6)  FMA2(wB.w, 7)   \
      FMA2(wC.x, 8)  FMA2(wC.y, 9)  FMA2(wC.z,10)  FMA2(wC.w,11)   \
      FMA2(wD.x,12)  FMA2(wD.y,13)  FMA2(wD.z,14)  FMA2(wD.w,15)   \
    } }

__global__ __launch_bounds__(256, 6) void k_c2(const float* __restrict__ p1,
        const float* __restrict__ w2, const float* __restrict__ b2,
        float* __restrict__ p2)
{
    __shared__ float s_in[12*14*38];     // 25,536 B  [r 0..11][ic][cc pad38]
    const int b   = blockIdx.z;
    const int ty0 = blockIdx.y * 4, tx0 = blockIdx.x * 16;   // pooled origin
    const int tid = threadIdx.x;

    // stage 12 input rows x 36 cols x 14 ic (conv rows 8*by .. +7 need
    // input rows 8*by .. +11)
    for (int i = tid; i < 12*36*14; i += 256) {
        int ic = i % 14, rem = i / 14;
        int cc = rem % 36, r = rem / 36;
        int gy = 2*ty0 + r, gx = 2*tx0 + cc;
        float v = 0.f;
        if (gy < 126 && gx < 126) v = p1[((long)(b*126 + gy)*126 + gx)*14 + ic];
        s_in[(r*14 + ic)*38 + cc] = v;
    }
    __syncthreads();

    const int cg  = tid >> 7;            // 0..1, wave-uniform (bit 7)
    const int t   = tid & 127;
    const int py  = t >> 4;              // conv row in tile, 0..7
    const int ppx = t & 15;              // column pair, 0..15
    const int ocb = cg * 16;
    const int bx  = 2 * ppx;             // left conv col (even)

    // Opaque VGPR copy of the weight base: prevents the compiler from
    // proving uniformity -> weight loads become global_load_dwordx4 (VMEM,
    // vmcnt) instead of s_load (SMEM, out-of-order lgkm). Value unchanged.
    const float* wb = w2 + ocb;
    asm("" : "+v"(wb));

    float accL[16], accR[16];
    #pragma unroll
    for (int c = 0; c < 16; ++c) { accL[c] = 0.f; accR[c] = 0.f; }

    for (int ky = 0; ky < 5; ++ky) {
        const float* rp = &s_in[((py + ky)*14)*38 + bx];
        float2 X[14], Y[14];
        #pragma unroll
        for (int ic = 0; ic < 14; ++ic)
            X[ic] = *reinterpret_cast<const float2*>(rp + ic*38);      // cols bx,bx+1
        #pragma unroll
        for (int ic = 0; ic < 14; ++ic)
            Y[ic] = *reinterpret_cast<const float2*>(rp + ic*38 + 2);  // cols bx+2,bx+3
        C2_BLOCK(0, X[ic].x, X[ic].y)      // cols (bx+0, bx+1)
        C2_BLOCK(1, X[ic].y, Y[ic].x)      // cols (bx+1, bx+2)
        C2_BLOCK(2, Y[ic].x, Y[ic].y)      // cols (bx+2, bx+3)
        #pragma unroll
        for (int ic = 0; ic < 14; ++ic)
            X[ic] = *reinterpret_cast<const float2*>(rp + ic*38 + 4);  // cols bx+4,bx+5
        C2_BLOCK(3, Y[ic].y, X[ic].x)      // cols (bx+3, bx+4)
        C2_BLOCK(4, X[ic].x, X[ic].y)      // cols (bx+4, bx+5)
    }

    // pool: own row pair-of-cols + partner row (py^1 == lane^16, same wave).
    // R7 order (0,0),(0,1),(1,0),(1,1): max is order-invariant, bit-exact.
    const int prow = ty0 + (py >> 1);
    const int pcol = tx0 + ppx;
    const bool wr = ((py & 1) == 0) && prow < 61 && pcol < 61;
    float* op = &p2[(long)b*119072 + (long)(prow*61 + pcol)*32 + ocb];
    #pragma unroll
    for (int c = 0; c < 16; ++c) {
        float bb = b2[ocb + c];
        float m0 = fmaxf(__fadd_rn(accL[c], bb), 0.f);
        m0 = fmaxf(m0, fmaxf(__fadd_rn(accR[c], bb), 0.f));
        float m1 = __shfl_xor(m0, 16, 64);
        if (wr) op[c] = fmaxf(m0, m1);
    }
}

// ======= dense1 phase A: per-panel partials (bit-exact R7 panel chains) ====
// grid (311, 4): panel p, batch-group of 32 (R13 config; batch-16 regressed
// by doubling d1_w re-fetch). thread = column n.
// part[p][b][n] = sum_{k in panel p} p2[b][k]*w[k][n]  (sequential k FMA)
__global__ __launch_bounds__(128) void k_d1a(const float* __restrict__ p2,
        const float* __restrict__ w, float* __restrict__ part)
{
    const int n = threadIdx.x;
    const int panel = blockIdx.x;
    const int b0 = blockIdx.y * 32;
    if (n >= 120) return;
    const int kp = panel * 384;
    const int ke = (kp + 384 < 119072) ? kp + 384 : 119072;
    const float* a0 = p2 + (long)b0 * 119072;
    float p[32];
    #pragma unroll
    for (int i = 0; i < 32; ++i) p[i] = 0.f;
    for (int k = kp; k < ke; ++k) {
        float wv = w[(long)k * 120 + n];
        #pragma unroll
        for (int i = 0; i < 32; ++i)
            p[i] = fmaf(a0[(long)i * 119072 + k], wv, p[i]);
    }
    #pragma unroll
    for (int i = 0; i < 32; ++i)
        part[((long)panel * 128 + b0 + i) * 120 + n] = p[i];
}

// ======= dense1 phase B: in-order panel sum (== R7 h accumulation) =======
__global__ __launch_bounds__(128) void k_d1b(const float* __restrict__ part,
        float* __restrict__ h1)
{
    const int b = blockIdx.x, n = threadIdx.x;
    if (n >= 120) return;
    float h = 0.f;
    for (int p = 0; p < 311; ++p)
        h = __fadd_rn(h, part[((long)p * 128 + b) * 120 + n]);
    h1[b * 120 + n] = h;
}

// ======= head: relu(h1+b1) -> d2+relu -> d3+b -> theta, f32 seq-FMA =======
__global__ __launch_bounds__(128) void k_head(const float* __restrict__ h1,
        const float* __restrict__ d1b, const float* __restrict__ d2w,
        const float* __restrict__ d2b, const float* __restrict__ d3w,
        const float* __restrict__ d3b, float* __restrict__ theta)
{
    __shared__ float s1[120], s2[84];
    const int b = blockIdx.x, t = threadIdx.x;
    if (t < 120) s1[t] = fmaxf(__fadd_rn(h1[b * 120 + t], d1b[t]), 0.f);
    __syncthreads();
    if (t < 84) {
        float a = 0.f;
        for (int k = 0; k < 120; ++k) a = fmaf(s1[k], d2w[k * 84 + t], a);
        s2[t] = fmaxf(__fadd_rn(a, d2b[t]), 0.f);
    }
    __syncthreads();
    if (t < 6) {
        float a = 0.f;
        for (int k = 0; k < 84; ++k) a = fmaf(s2[k], d3w[k * 6 + t], a);
        theta[b * 6 + t] = __fadd_rn(a, d3b[t]);
    }
}

// ======= sampler: strict f32 reference expression tree (== R7) =======
__global__ __launch_bounds__(256) void k_sample(const float* __restrict__ x,
        const float* __restrict__ theta, const float* __restrict__ ow,
        const float* __restrict__ ob, float* __restrict__ out)
{
    const int idx = blockIdx.x * 256 + threadIdx.x;   // < 128*65536
    const int b   = idx >> 16;
    const int pix = idx & 65535;
    const int yy  = pix >> 8, xx = pix & 255;
    const float gx = __fadd_rn((float)xx * (1.f / 128.f), -1.f);
    const float gy = __fadd_rn((float)yy * (1.f / 128.f), -1.f);
    const float* th = &theta[b * 6];
    float rx = __fmul_rn(th[0], gx);
    rx = fmaf(th[1], gy, rx);
    rx = __fadd_rn(rx, th[2]);
    float ry = __fmul_rn(th[3], gx);
    ry = fmaf(th[4], gy, ry);
    ry = __fadd_rn(ry, th[5]);
    const float px = __fmul_rn(__fmul_rn(__fadd_rn(rx, 1.f), 0.5f), 256.f);
    const float py = __fmul_rn(__fmul_rn(__fadd_rn(ry, 1.f), 0.5f), 256.f);
    int x1 = (int)floorf(px), y1 = (int)floorf(py);
    int x2 = x1 + 1,  y2 = y1 + 1;
    x1 = min(max(x1, 0), 255); x2 = min(max(x2, 0), 255);
    y1 = min(max(y1, 0), 255); y2 = min(max(y2, 0), 255);
    const float* img = x + (long)b * 65536;
    const float p11 = img[y1 * 256 + x1];
    const float p12 = img[y2 * 256 + x1];
    const float p21 = img[y1 * 256 + x2];
    const float p22 = img[y2 * 256 + x2];
    const float wx1 = __fsub_rn((float)x2, px);
    const float wx2 = __fsub_rn(px, (float)x1);
    const float wy1 = __fsub_rn((float)y2, py);
    const float wy2 = __fsub_rn(py, (float)y1);
    const float sa = __fadd_rn(__fmul_rn(wy1, p11), __fmul_rn(wy2, p12));
    const float sb = __fadd_rn(__fmul_rn(wy1, p21), __fmul_rn(wy2, p22));
    const float r  = __fadd_rn(__fmul_rn(wx1, sa), __fmul_rn(wx2, sb));
    const float o  = __fadd_rn(__fmul_rn(r, ow[0]), ob[0]);
    out[idx] = 1.f / (1.f + expf(-o));
}

extern "C" void kernel_launch(void* const* d_in, const int* in_sizes, int n_in,
                              void* d_out, int out_size, void* d_ws, size_t ws_size,
                              hipStream_t stream)
{
    const float* x   = (const float*)d_in[0];
    const float* c1w = (const float*)d_in[1];
    const float* c1b = (const float*)d_in[2];
    const float* c2w = (const float*)d_in[3];
    const float* c2b = (const float*)d_in[4];
    const float* d1w = (const float*)d_in[5];
    const float* d1b = (const float*)d_in[6];
    const float* d2w = (const float*)d_in[7];
    const float* d2b = (const float*)d_in[8];
    const float* d3w = (const float*)d_in[9];
    const float* d3b = (const float*)d_in[10];
    const float* ow  = (const float*)d_in[11];
    const float* ob  = (const float*)d_in[12];

    char*  ws   = (char*)d_ws;
    float* th   = (float*)(ws + TH_OFF);
    float* h1   = (float*)(ws + H1_OFF);
    float* p1   = (float*)(ws + P1_OFF);
    float* part = (float*)(ws + PART_OFF);   // reuses p1 space (p1 dead)
    float* p2   = (float*)(ws + P2_OFF);

    k_c1    <<<dim3(8, 8, 128),   256, 0, stream>>>(x, c1w, c1b, p1);
    k_c2    <<<dim3(4, 16, 128),  256, 0, stream>>>(p1, c2w, c2b, p2);
    k_d1a   <<<dim3(311, 4),      128, 0, stream>>>(p2, d1w, part);
    k_d1b   <<<dim3(128),         128, 0, stream>>>(part, h1);
    k_head  <<<dim3(128),         128, 0, stream>>>(h1, d1b, d2w, d2b, d3w, d3b, th);
    k_sample<<<dim3(32768),       256, 0, stream>>>(x, th, ow, ob, (float*)d_out);
}

// Round 8
// 1072.242 us; speedup vs baseline: 2.6907x; 2.6907x over previous
//
#include <hip/hip_runtime.h>

// R16: best-of assembly after R15's failed experiment.
//  - k_c2: byte-for-byte revert to R14 v5 (PROVEN 540us): 256-thr blocks,
//    8-conv-row tiles, LDS s_in[12][14][38], scalar s_load weight path via
//    readfirstlane(cg). R15's opaque-asm VGPR weight base destroyed CSE ->
//    FETCH 1GB, WRITE 2.1GB, 2287us. Never force weight base to VGPR.
//  - k_d1a: batch-group 32 (R13 config), but 256 threads: two waves split
//    the 32 batches (16 each). Same grid/traffic (w reads L1-shared),
//    double the resident waves for latency hiding. Chains bit-identical.
// All arithmetic chains byte-identical to R13/R14 (PASSED, 0.00390625).
// NUMERICS CONTRACT (do not violate): golden is faithful float32 numpy;
// border-degenerate bilinear pixels flip discontinuously on ~1e-6 theta
// changes. Every conv/dense output must keep its exact sequential chain
// ((ky,kx) for conv1, (ky,kx,ic) for conv2, panel-k for dense1).
//
// ---- workspace (bytes), ~175MB ----
// th   f32[128*6]            @ 0
// h1   f32[128*120]          @ 4096
// p1   f32 NHWC [128][126][126][14] @ 65536      (113,799,168 B)
// part f32[311][128][120]    @ 65536  (19,107,840 B; overlaps p1: p1 is dead
//                                      before k_d1a writes part)
// p2   f32[128][119072]      @ 113930240         (60,964,864 B)
#define TH_OFF   0ull
#define H1_OFF   4096ull
#define P1_OFF   65536ull
#define PART_OFF 65536ull
#define P2_OFF   113930240ull

// ======= conv1 5x5 (1->14) + bias + relu + maxpool2, tiled =======
// block: 16x16 pool outputs, 1 batch; p1 NHWC [126][126][14]
__global__ __launch_bounds__(256) void k_c1(const float* __restrict__ x,
        const float* __restrict__ w1, const float* __restrict__ b1,
        float* __restrict__ p1)
{
    __shared__ float s_in[36*36];
    __shared__ float s_w[350];
    __shared__ float s_b[14];
    const int b   = blockIdx.z;
    const int ty0 = blockIdx.y * 16, tx0 = blockIdx.x * 16;
    const int tid = threadIdx.x;
    for (int i = tid; i < 36*36; i += 256) {
        int r = i / 36, c = i % 36;
        int gy = 2*ty0 + r, gx = 2*tx0 + c;
        float v = 0.f;
        if (gy < 256 && gx < 256) v = x[(long)(b*256 + gy)*256 + gx];
        s_in[i] = v;
    }
    for (int i = tid; i < 350; i += 256) s_w[i] = w1[i];
    if (tid < 14) s_b[tid] = b1[tid];
    __syncthreads();

    const int py = tid >> 4, px = tid & 15;
    float a0[14], a1[14], a2[14], a3[14];
    #pragma unroll
    for (int c = 0; c < 14; ++c) { a0[c]=0.f; a1[c]=0.f; a2[c]=0.f; a3[c]=0.f; }
    const int iy = 2*py, ix = 2*px;
    // chain order per accumulator: (ky,kx) sequential == R7
    #pragma unroll
    for (int ky = 0; ky < 5; ++ky) {
      #pragma unroll
      for (int kx = 0; kx < 5; ++kx) {
        float wv[14];
        #pragma unroll
        for (int c = 0; c < 14; ++c) wv[c] = s_w[(ky*5+kx)*14 + c];
        const float* ip = &s_in[(iy+ky)*36 + ix + kx];
        float v00 = ip[0],  v01 = ip[1];
        float v10 = ip[36], v11 = ip[37];
        #pragma unroll
        for (int c = 0; c < 14; ++c) {
            a0[c] = fmaf(v00, wv[c], a0[c]);
            a1[c] = fmaf(v01, wv[c], a1[c]);
            a2[c] = fmaf(v10, wv[c], a2[c]);
            a3[c] = fmaf(v11, wv[c], a3[c]);
        }
      }
    }
    const int oy = ty0 + py, ox = tx0 + px;
    if (oy < 126 && ox < 126) {
        float* op = &p1[((long)(b*126 + oy)*126 + ox)*14];
        #pragma unroll
        for (int c = 0; c < 14; ++c) {
            float bb = s_b[c];
            // R7 pool order: (0,0),(0,1),(1,0),(1,1)
            float m = fmaxf(__fadd_rn(a0[c], bb), 0.f);
            m = fmaxf(m, fmaxf(__fadd_rn(a1[c], bb), 0.f));
            m = fmaxf(m, fmaxf(__fadd_rn(a2[c], bb), 0.f));
            m = fmaxf(m, fmaxf(__fadd_rn(a3[c], bb), 0.f));
            op[c] = m;
        }
    }
}

// ======= conv2 5x5 (14->32) + bias + relu + maxpool2 (v5 == R14) =======
// block: 256 thr = 128 pos (8 conv rows x 16 col-pairs) x 2 oc-groups(16).
// LDS: s_in[12][14][38] = 25,536 B -> 6 blocks/CU; 8192 blocks.
// Weights: GLOBAL w2 at readfirstlane-uniform address -> scalar s_load /
// L1-hit uniform loads; zero LDS-pipe cost. (Do NOT force VGPR base: R15.)
// s_in layout [r][ic][cc pad 38]: conflict-free ds_read_b64 column pairs.
// Per-output FMA chain (ky,kx,ic) sequential == R7/R8. Pool across partner
// row via shfl_xor(16); fmaxf is order-invariant => bit-exact.
#define C2_BLOCK(KX, VL, VR)                                        \
  { const int kb = (ky*5 + (KX))*14;                                \
    _Pragma("unroll")                                               \
    for (int ic = 0; ic < 14; ++ic) {                               \
      const float* wp = &w2[(kb + ic)*32 + ocb];                    \
      float4 wA = *reinterpret_cast<const float4*>(wp);             \
      float4 wB = *reinterpret_cast<const float4*>(wp + 4);         \
      float4 wC = *reinterpret_cast<const float4*>(wp + 8);         \
      float4 wD = *reinterpret_cast<const float4*>(wp + 12);        \
      float wv[16] = {wA.x,wA.y,wA.z,wA.w, wB.x,wB.y,wB.z,wB.w,     \
                      wC.x,wC.y,wC.z,wC.w, wD.x,wD.y,wD.z,wD.w};    \
      float vl = (VL), vr = (VR);                                   \
      _Pragma("unroll")                                             \
      for (int c = 0; c < 16; ++c) {                                \
        accL[c] = fmaf(vl, wv[c], accL[c]);                         \
        accR[c] = fmaf(vr, wv[c], accR[c]);                         \
      } } }

__global__ __launch_bounds__(256) void k_c2(const float* __restrict__ p1,
        const float* __restrict__ w2, const float* __restrict__ b2,
        float* __restrict__ p2)
{
    __shared__ float s_in[12*14*38];     // 25,536 B  [r 0..11][ic][cc pad38]
    const int b   = blockIdx.z;
    const int ty0 = blockIdx.y * 4, tx0 = blockIdx.x * 16;   // pooled origin
    const int tid = threadIdx.x;

    // stage 12 input rows x 36 cols x 14 ic (conv rows 8*by .. +7 need
    // input rows 8*by .. +11)
    for (int i = tid; i < 12*36*14; i += 256) {
        int ic = i % 14, rem = i / 14;
        int cc = rem % 36, r = rem / 36;
        int gy = 2*ty0 + r, gx = 2*tx0 + cc;
        float v = 0.f;
        if (gy < 126 && gx < 126) v = p1[((long)(b*126 + gy)*126 + gx)*14 + ic];
        s_in[(r*14 + ic)*38 + cc] = v;
    }
    __syncthreads();

    // cg (tid bit 7) is uniform within each 64-lane wave; readfirstlane makes
    // that provable -> weight addresses become scalar (s_load path).
    const int cg  = __builtin_amdgcn_readfirstlane(tid >> 7);  // 0..1
    const int t   = tid & 127;
    const int py  = t >> 4;              // conv row in tile, 0..7
    const int ppx = t & 15;              // column pair, 0..15
    const int ocb = cg * 16;
    const int bx  = 2 * ppx;             // left conv col (even)

    float accL[16], accR[16];
    #pragma unroll
    for (int c = 0; c < 16; ++c) { accL[c] = 0.f; accR[c] = 0.f; }

    for (int ky = 0; ky < 5; ++ky) {
        const float* rp = &s_in[((py + ky)*14)*38 + bx];
        float2 X[14], Y[14];
        #pragma unroll
        for (int ic = 0; ic < 14; ++ic)
            X[ic] = *reinterpret_cast<const float2*>(rp + ic*38);      // cols bx,bx+1
        #pragma unroll
        for (int ic = 0; ic < 14; ++ic)
            Y[ic] = *reinterpret_cast<const float2*>(rp + ic*38 + 2);  // cols bx+2,bx+3
        C2_BLOCK(0, X[ic].x, X[ic].y)      // cols (bx+0, bx+1)
        C2_BLOCK(1, X[ic].y, Y[ic].x)      // cols (bx+1, bx+2)
        C2_BLOCK(2, Y[ic].x, Y[ic].y)      // cols (bx+2, bx+3)
        #pragma unroll
        for (int ic = 0; ic < 14; ++ic)
            X[ic] = *reinterpret_cast<const float2*>(rp + ic*38 + 4);  // cols bx+4,bx+5
        C2_BLOCK(3, Y[ic].y, X[ic].x)      // cols (bx+3, bx+4)
        C2_BLOCK(4, X[ic].x, X[ic].y)      // cols (bx+4, bx+5)
    }

    // pool: own row pair-of-cols + partner row (py^1 == lane^16, same wave).
    // R7 order (0,0),(0,1),(1,0),(1,1): max is order-invariant, bit-exact.
    const int prow = ty0 + (py >> 1);
    const int pcol = tx0 + ppx;
    const bool wr = ((py & 1) == 0) && prow < 61 && pcol < 61;
    float* op = &p2[(long)b*119072 + (long)(prow*61 + pcol)*32 + ocb];
    #pragma unroll
    for (int c = 0; c < 16; ++c) {
        float bb = b2[ocb + c];
        float m0 = fmaxf(__fadd_rn(accL[c], bb), 0.f);
        m0 = fmaxf(m0, fmaxf(__fadd_rn(accR[c], bb), 0.f));
        float m1 = __shfl_xor(m0, 16, 64);
        if (wr) op[c] = fmaxf(m0, m1);
    }
}

// ======= dense1 phase A: per-panel partials (bit-exact R7 panel chains) ====
// grid (311, 4), 256 thr: panel p, batch-group of 32 SPLIT across two waves
// (wave 0: b0..b0+15, wave 1: b0+16..b0+31). Same traffic as R13 (w reads
// shared via L1), 2x resident waves. thread = (half, column n).
// part[p][b][n] = sum_{k in panel p} p2[b][k]*w[k][n]  (sequential k FMA)
__global__ __launch_bounds__(256) void k_d1a(const float* __restrict__ p2,
        const float* __restrict__ w, float* __restrict__ part)
{
    const int n = threadIdx.x & 127;
    const int half = threadIdx.x >> 7;           // 0..1, wave-uniform
    const int panel = blockIdx.x;
    const int b0 = blockIdx.y * 32 + half * 16;
    if (n >= 120) return;
    const int kp = panel * 384;
    const int ke = (kp + 384 < 119072) ? kp + 384 : 119072;
    const float* a0 = p2 + (long)b0 * 119072;
    float p[16];
    #pragma unroll
    for (int i = 0; i < 16; ++i) p[i] = 0.f;
    for (int k = kp; k < ke; ++k) {
        float wv = w[(long)k * 120 + n];
        #pragma unroll
        for (int i = 0; i < 16; ++i)
            p[i] = fmaf(a0[(long)i * 119072 + k], wv, p[i]);
    }
    #pragma unroll
    for (int i = 0; i < 16; ++i)
        part[((long)panel * 128 + b0 + i) * 120 + n] = p[i];
}

// ======= dense1 phase B: in-order panel sum (== R7 h accumulation) =======
__global__ __launch_bounds__(128) void k_d1b(const float* __restrict__ part,
        float* __restrict__ h1)
{
    const int b = blockIdx.x, n = threadIdx.x;
    if (n >= 120) return;
    float h = 0.f;
    for (int p = 0; p < 311; ++p)
        h = __fadd_rn(h, part[((long)p * 128 + b) * 120 + n]);
    h1[b * 120 + n] = h;
}

// ======= head: relu(h1+b1) -> d2+relu -> d3+b -> theta, f32 seq-FMA =======
__global__ __launch_bounds__(128) void k_head(const float* __restrict__ h1,
        const float* __restrict__ d1b, const float* __restrict__ d2w,
        const float* __restrict__ d2b, const float* __restrict__ d3w,
        const float* __restrict__ d3b, float* __restrict__ theta)
{
    __shared__ float s1[120], s2[84];
    const int b = blockIdx.x, t = threadIdx.x;
    if (t < 120) s1[t] = fmaxf(__fadd_rn(h1[b * 120 + t], d1b[t]), 0.f);
    __syncthreads();
    if (t < 84) {
        float a = 0.f;
        for (int k = 0; k < 120; ++k) a = fmaf(s1[k], d2w[k * 84 + t], a);
        s2[t] = fmaxf(__fadd_rn(a, d2b[t]), 0.f);
    }
    __syncthreads();
    if (t < 6) {
        float a = 0.f;
        for (int k = 0; k < 84; ++k) a = fmaf(s2[k], d3w[k * 6 + t], a);
        theta[b * 6 + t] = __fadd_rn(a, d3b[t]);
    }
}

// ======= sampler: strict f32 reference expression tree (== R7) =======
__global__ __launch_bounds__(256) void k_sample(const float* __restrict__ x,
        const float* __restrict__ theta, const float* __restrict__ ow,
        const float* __restrict__ ob, float* __restrict__ out)
{
    const int idx = blockIdx.x * 256 + threadIdx.x;   // < 128*65536
    const int b   = idx >> 16;
    const int pix = idx & 65535;
    const int yy  = pix >> 8, xx = pix & 255;
    const float gx = __fadd_rn((float)xx * (1.f / 128.f), -1.f);
    const float gy = __fadd_rn((float)yy * (1.f / 128.f), -1.f);
    const float* th = &theta[b * 6];
    float rx = __fmul_rn(th[0], gx);
    rx = fmaf(th[1], gy, rx);
    rx = __fadd_rn(rx, th[2]);
    float ry = __fmul_rn(th[3], gx);
    ry = fmaf(th[4], gy, ry);
    ry = __fadd_rn(ry, th[5]);
    const float px = __fmul_rn(__fmul_rn(__fadd_rn(rx, 1.f), 0.5f), 256.f);
    const float py = __fmul_rn(__fmul_rn(__fadd_rn(ry, 1.f), 0.5f), 256.f);
    int x1 = (int)floorf(px), y1 = (int)floorf(py);
    int x2 = x1 + 1,  y2 = y1 + 1;
    x1 = min(max(x1, 0), 255); x2 = min(max(x2, 0), 255);
    y1 = min(max(y1, 0), 255); y2 = min(max(y2, 0), 255);
    const float* img = x + (long)b * 65536;
    const float p11 = img[y1 * 256 + x1];
    const float p12 = img[y2 * 256 + x1];
    const float p21 = img[y1 * 256 + x2];
    const float p22 = img[y2 * 256 + x2];
    const float wx1 = __fsub_rn((float)x2, px);
    const float wx2 = __fsub_rn(px, (float)x1);
    const float wy1 = __fsub_rn((float)y2, py);
    const float wy2 = __fsub_rn(py, (float)y1);
    const float sa = __fadd_rn(__fmul_rn(wy1, p11), __fmul_rn(wy2, p12));
    const float sb = __fadd_rn(__fmul_rn(wy1, p21), __fmul_rn(wy2, p22));
    const float r  = __fadd_rn(__fmul_rn(wx1, sa), __fmul_rn(wx2, sb));
    const float o  = __fadd_rn(__fmul_rn(r, ow[0]), ob[0]);
    out[idx] = 1.f / (1.f + expf(-o));
}

extern "C" void kernel_launch(void* const* d_in, const int* in_sizes, int n_in,
                              void* d_out, int out_size, void* d_ws, size_t ws_size,
                              hipStream_t stream)
{
    const float* x   = (const float*)d_in[0];
    const float* c1w = (const float*)d_in[1];
    const float* c1b = (const float*)d_in[2];
    const float* c2w = (const float*)d_in[3];
    const float* c2b = (const float*)d_in[4];
    const float* d1w = (const float*)d_in[5];
    const float* d1b = (const float*)d_in[6];
    const float* d2w = (const float*)d_in[7];
    const float* d2b = (const float*)d_in[8];
    const float* d3w = (const float*)d_in[9];
    const float* d3b = (const float*)d_in[10];
    const float* ow  = (const float*)d_in[11];
    const float* ob  = (const float*)d_in[12];

    char*  ws   = (char*)d_ws;
    float* th   = (float*)(ws + TH_OFF);
    float* h1   = (float*)(ws + H1_OFF);
    float* p1   = (float*)(ws + P1_OFF);
    float* part = (float*)(ws + PART_OFF);   // reuses p1 space (p1 dead)
    float* p2   = (float*)(ws + P2_OFF);

    k_c1    <<<dim3(8, 8, 128),   256, 0, stream>>>(x, c1w, c1b, p1);
    k_c2    <<<dim3(4, 16, 128),  256, 0, stream>>>(p1, c2w, c2b, p2);
    k_d1a   <<<dim3(311, 4),      256, 0, stream>>>(p2, d1w, part);
    k_d1b   <<<dim3(128),         128, 0, stream>>>(part, h1);
    k_head  <<<dim3(128),         128, 0, stream>>>(h1, d1b, d2w, d2b, d3w, d3b, th);
    k_sample<<<dim3(32768),       256, 0, stream>>>(x, th, ow, ob, (float*)d_out);
}

// Round 10
// 1043.602 us; speedup vs baseline: 2.7646x; 1.0274x over previous
//
#include <hip/hip_runtime.h>

// R18 == R17 resubmitted verbatim (R17's bench was an infra failure:
// "MI355X container failed twice"; no counters, no verdict).
// R17: R16 + two low-risk, bit-exact de-bottleneckings of the non-c2 half
// (534us of 1072us total, none individually in the rocprof top-5):
//  - k_c1: weights+bias moved OFF the LDS pipe -> read directly from global
//    w1/b1 at thread-independent addresses (provably uniform -> s_load on
//    SMEM pipe). Exactly the fix that took k_c2 660->558 (R12). Values and
//    (ky,kx) chain order identical -> bit-exact.
//  - k_sample: b computed as blockIdx.x>>8 (256-thr blocks never straddle a
//    batch) -> theta loads become scalar s_load, image base lands in SGPRs.
//    Expression tree untouched -> bit-exact.
//  - k_c2 / k_d1a / k_d1b / k_head: byte-identical to R16 (PASSED, 1072us).
// NUMERICS CONTRACT (do not violate): golden is faithful float32 numpy;
// border-degenerate bilinear pixels flip discontinuously on ~1e-6 theta
// changes. Every conv/dense output must keep its exact sequential chain
// ((ky,kx) for conv1, (ky,kx,ic) for conv2, panel-k for dense1).
//
// ---- workspace (bytes), ~175MB ----
// th   f32[128*6]            @ 0
// h1   f32[128*120]          @ 4096
// p1   f32 NHWC [128][126][126][14] @ 65536      (113,799,168 B)
// part f32[311][128][120]    @ 65536  (19,107,840 B; overlaps p1: p1 is dead
//                                      before k_d1a writes part)
// p2   f32[128][119072]      @ 113930240         (60,964,864 B)
#define TH_OFF   0ull
#define H1_OFF   4096ull
#define P1_OFF   65536ull
#define PART_OFF 65536ull
#define P2_OFF   113930240ull

// ======= conv1 5x5 (1->14) + bias + relu + maxpool2, tiled (v2) =======
// block: 16x16 pool outputs, 1 batch; p1 NHWC [126][126][14]
// Weights/bias from GLOBAL at thread-independent (uniform) addresses ->
// SMEM s_load, zero LDS-pipe cost; LDS carries only the input tile.
__global__ __launch_bounds__(256) void k_c1(const float* __restrict__ x,
        const float* __restrict__ w1, const float* __restrict__ b1,
        float* __restrict__ p1)
{
    __shared__ float s_in[36*36];
    const int b   = blockIdx.z;
    const int ty0 = blockIdx.y * 16, tx0 = blockIdx.x * 16;
    const int tid = threadIdx.x;
    for (int i = tid; i < 36*36; i += 256) {
        int r = i / 36, c = i % 36;
        int gy = 2*ty0 + r, gx = 2*tx0 + c;
        float v = 0.f;
        if (gy < 256 && gx < 256) v = x[(long)(b*256 + gy)*256 + gx];
        s_in[i] = v;
    }
    __syncthreads();

    const int py = tid >> 4, px = tid & 15;
    float a0[14], a1[14], a2[14], a3[14];
    #pragma unroll
    for (int c = 0; c < 14; ++c) { a0[c]=0.f; a1[c]=0.f; a2[c]=0.f; a3[c]=0.f; }
    const int iy = 2*py, ix = 2*px;
    // chain order per accumulator: (ky,kx) sequential == R7
    #pragma unroll
    for (int ky = 0; ky < 5; ++ky) {
      #pragma unroll
      for (int kx = 0; kx < 5; ++kx) {
        float wv[14];
        #pragma unroll
        for (int c = 0; c < 14; ++c) wv[c] = w1[(ky*5+kx)*14 + c];  // uniform -> s_load
        const float* ip = &s_in[(iy+ky)*36 + ix + kx];
        float v00 = ip[0],  v01 = ip[1];
        float v10 = ip[36], v11 = ip[37];
        #pragma unroll
        for (int c = 0; c < 14; ++c) {
            a0[c] = fmaf(v00, wv[c], a0[c]);
            a1[c] = fmaf(v01, wv[c], a1[c]);
            a2[c] = fmaf(v10, wv[c], a2[c]);
            a3[c] = fmaf(v11, wv[c], a3[c]);
        }
      }
    }
    const int oy = ty0 + py, ox = tx0 + px;
    if (oy < 126 && ox < 126) {
        float* op = &p1[((long)(b*126 + oy)*126 + ox)*14];
        #pragma unroll
        for (int c = 0; c < 14; ++c) {
            float bb = b1[c];                       // uniform -> s_load
            // R7 pool order: (0,0),(0,1),(1,0),(1,1)
            float m = fmaxf(__fadd_rn(a0[c], bb), 0.f);
            m = fmaxf(m, fmaxf(__fadd_rn(a1[c], bb), 0.f));
            m = fmaxf(m, fmaxf(__fadd_rn(a2[c], bb), 0.f));
            m = fmaxf(m, fmaxf(__fadd_rn(a3[c], bb), 0.f));
            op[c] = m;
        }
    }
}

// ======= conv2 5x5 (14->32) + bias + relu + maxpool2 (v5 == R14/R16) =====
// block: 256 thr = 128 pos (8 conv rows x 16 col-pairs) x 2 oc-groups(16).
// LDS: s_in[12][14][38] = 25,536 B -> 6 blocks/CU; 8192 blocks.
// Weights: GLOBAL w2 at readfirstlane-uniform address -> scalar s_load /
// L1-hit uniform loads; zero LDS-pipe cost. (Do NOT force VGPR base: R15.)
// s_in layout [r][ic][cc pad 38]: conflict-free ds_read_b64 column pairs.
// Per-output FMA chain (ky,kx,ic) sequential == R7/R8. Pool across partner
// row via shfl_xor(16); fmaxf is order-invariant => bit-exact.
#define C2_BLOCK(KX, VL, VR)                                        \
  { const int kb = (ky*5 + (KX))*14;                                \
    _Pragma("unroll")                                               \
    for (int ic = 0; ic < 14; ++ic) {                               \
      const float* wp = &w2[(kb + ic)*32 + ocb];                    \
      float4 wA = *reinterpret_cast<const float4*>(wp);             \
      float4 wB = *reinterpret_cast<const float4*>(wp + 4);         \
      float4 wC = *reinterpret_cast<const float4*>(wp + 8);         \
      float4 wD = *reinterpret_cast<const float4*>(wp + 12);        \
      float wv[16] = {wA.x,wA.y,wA.z,wA.w, wB.x,wB.y,wB.z,wB.w,     \
                      wC.x,wC.y,wC.z,wC.w, wD.x,wD.y,wD.z,wD.w};    \
      float vl = (VL), vr = (VR);                                   \
      _Pragma("unroll")                                             \
      for (int c = 0; c < 16; ++c) {                                \
        accL[c] = fmaf(vl, wv[c], accL[c]);                         \
        accR[c] = fmaf(vr, wv[c], accR[c]);                         \
      } } }

__global__ __launch_bounds__(256) void k_c2(const float* __restrict__ p1,
        const float* __restrict__ w2, const float* __restrict__ b2,
        float* __restrict__ p2)
{
    __shared__ float s_in[12*14*38];     // 25,536 B  [r 0..11][ic][cc pad38]
    const int b   = blockIdx.z;
    const int ty0 = blockIdx.y * 4, tx0 = blockIdx.x * 16;   // pooled origin
    const int tid = threadIdx.x;

    // stage 12 input rows x 36 cols x 14 ic (conv rows 8*by .. +7 need
    // input rows 8*by .. +11)
    for (int i = tid; i < 12*36*14; i += 256) {
        int ic = i % 14, rem = i / 14;
        int cc = rem % 36, r = rem / 36;
        int gy = 2*ty0 + r, gx = 2*tx0 + cc;
        float v = 0.f;
        if (gy < 126 && gx < 126) v = p1[((long)(b*126 + gy)*126 + gx)*14 + ic];
        s_in[(r*14 + ic)*38 + cc] = v;
    }
    __syncthreads();

    // cg (tid bit 7) is uniform within each 64-lane wave; readfirstlane makes
    // that provable -> weight addresses become scalar (s_load path).
    const int cg  = __builtin_amdgcn_readfirstlane(tid >> 7);  // 0..1
    const int t   = tid & 127;
    const int py  = t >> 4;              // conv row in tile, 0..7
    const int ppx = t & 15;              // column pair, 0..15
    const int ocb = cg * 16;
    const int bx  = 2 * ppx;             // left conv col (even)

    float accL[16], accR[16];
    #pragma unroll
    for (int c = 0; c < 16; ++c) { accL[c] = 0.f; accR[c] = 0.f; }

    for (int ky = 0; ky < 5; ++ky) {
        const float* rp = &s_in[((py + ky)*14)*38 + bx];
        float2 X[14], Y[14];
        #pragma unroll
        for (int ic = 0; ic < 14; ++ic)
            X[ic] = *reinterpret_cast<const float2*>(rp + ic*38);      // cols bx,bx+1
        #pragma unroll
        for (int ic = 0; ic < 14; ++ic)
            Y[ic] = *reinterpret_cast<const float2*>(rp + ic*38 + 2);  // cols bx+2,bx+3
        C2_BLOCK(0, X[ic].x, X[ic].y)      // cols (bx+0, bx+1)
        C2_BLOCK(1, X[ic].y, Y[ic].x)      // cols (bx+1, bx+2)
        C2_BLOCK(2, Y[ic].x, Y[ic].y)      // cols (bx+2, bx+3)
        #pragma unroll
        for (int ic = 0; ic < 14; ++ic)
            X[ic] = *reinterpret_cast<const float2*>(rp + ic*38 + 4);  // cols bx+4,bx+5
        C2_BLOCK(3, Y[ic].y, X[ic].x)      // cols (bx+3, bx+4)
        C2_BLOCK(4, X[ic].x, X[ic].y)      // cols (bx+4, bx+5)
    }

    // pool: own row pair-of-cols + partner row (py^1 == lane^16, same wave).
    // R7 order (0,0),(0,1),(1,0),(1,1): max is order-invariant, bit-exact.
    const int prow = ty0 + (py >> 1);
    const int pcol = tx0 + ppx;
    const bool wr = ((py & 1) == 0) && prow < 61 && pcol < 61;
    float* op = &p2[(long)b*119072 + (long)(prow*61 + pcol)*32 + ocb];
    #pragma unroll
    for (int c = 0; c < 16; ++c) {
        float bb = b2[ocb + c];
        float m0 = fmaxf(__fadd_rn(accL[c], bb), 0.f);
        m0 = fmaxf(m0, fmaxf(__fadd_rn(accR[c], bb), 0.f));
        float m1 = __shfl_xor(m0, 16, 64);
        if (wr) op[c] = fmaxf(m0, m1);
    }
}

// ======= dense1 phase A: per-panel partials (bit-exact R7 panel chains) ====
// grid (311, 4), 256 thr: panel p, batch-group of 32 SPLIT across two waves
// (wave 0: b0..b0+15, wave 1: b0+16..b0+31). Same traffic as R13 (w reads
// shared via L1), 2x resident waves. thread = (half, column n).
// part[p][b][n] = sum_{k in panel p} p2[b][k]*w[k][n]  (sequential k FMA)
__global__ __launch_bounds__(256) void k_d1a(const float* __restrict__ p2,
        const float* __restrict__ w, float* __restrict__ part)
{
    const int n = threadIdx.x & 127;
    const int half = threadIdx.x >> 7;           // 0..1, wave-uniform
    const int panel = blockIdx.x;
    const int b0 = blockIdx.y * 32 + half * 16;
    if (n >= 120) return;
    const int kp = panel * 384;
    const int ke = (kp + 384 < 119072) ? kp + 384 : 119072;
    const float* a0 = p2 + (long)b0 * 119072;
    float p[16];
    #pragma unroll
    for (int i = 0; i < 16; ++i) p[i] = 0.f;
    for (int k = kp; k < ke; ++k) {
        float wv = w[(long)k * 120 + n];
        #pragma unroll
        for (int i = 0; i < 16; ++i)
            p[i] = fmaf(a0[(long)i * 119072 + k], wv, p[i]);
    }
    #pragma unroll
    for (int i = 0; i < 16; ++i)
        part[((long)panel * 128 + b0 + i) * 120 + n] = p[i];
}

// ======= dense1 phase B: in-order panel sum (== R7 h accumulation) =======
__global__ __launch_bounds__(128) void k_d1b(const float* __restrict__ part,
        float* __restrict__ h1)
{
    const int b = blockIdx.x, n = threadIdx.x;
    if (n >= 120) return;
    float h = 0.f;
    for (int p = 0; p < 311; ++p)
        h = __fadd_rn(h, part[((long)p * 128 + b) * 120 + n]);
    h1[b * 120 + n] = h;
}

// ======= head: relu(h1+b1) -> d2+relu -> d3+b -> theta, f32 seq-FMA =======
__global__ __launch_bounds__(128) void k_head(const float* __restrict__ h1,
        const float* __restrict__ d1b, const float* __restrict__ d2w,
        const float* __restrict__ d2b, const float* __restrict__ d3w,
        const float* __restrict__ d3b, float* __restrict__ theta)
{
    __shared__ float s1[120], s2[84];
    const int b = blockIdx.x, t = threadIdx.x;
    if (t < 120) s1[t] = fmaxf(__fadd_rn(h1[b * 120 + t], d1b[t]), 0.f);
    __syncthreads();
    if (t < 84) {
        float a = 0.f;
        for (int k = 0; k < 120; ++k) a = fmaf(s1[k], d2w[k * 84 + t], a);
        s2[t] = fmaxf(__fadd_rn(a, d2b[t]), 0.f);
    }
    __syncthreads();
    if (t < 6) {
        float a = 0.f;
        for (int k = 0; k < 84; ++k) a = fmaf(s2[k], d3w[k * 6 + t], a);
        theta[b * 6 + t] = __fadd_rn(a, d3b[t]);
    }
}

// ======= sampler: strict f32 reference expression tree (== R7) =======
// b is block-uniform (256-thr blocks never straddle a batch): computing it
// from blockIdx makes theta loads scalar s_load + image base SGPR-resident.
__global__ __launch_bounds__(256) void k_sample(const float* __restrict__ x,
        const float* __restrict__ theta, const float* __restrict__ ow,
        const float* __restrict__ ob, float* __restrict__ out)
{
    const int b   = blockIdx.x >> 8;                  // uniform
    const int pix = ((blockIdx.x & 255) << 8) | threadIdx.x;
    const int idx = (b << 16) | pix;
    const int yy  = pix >> 8, xx = pix & 255;
    const float gx = __fadd_rn((float)xx * (1.f / 128.f), -1.f);
    const float gy = __fadd_rn((float)yy * (1.f / 128.f), -1.f);
    const float* th = &theta[b * 6];
    float rx = __fmul_rn(th[0], gx);
    rx = fmaf(th[1], gy, rx);
    rx = __fadd_rn(rx, th[2]);
    float ry = __fmul_rn(th[3], gx);
    ry = fmaf(th[4], gy, ry);
    ry = __fadd_rn(ry, th[5]);
    const float px = __fmul_rn(__fmul_rn(__fadd_rn(rx, 1.f), 0.5f), 256.f);
    const float py = __fmul_rn(__fmul_rn(__fadd_rn(ry, 1.f), 0.5f), 256.f);
    int x1 = (int)floorf(px), y1 = (int)floorf(py);
    int x2 = x1 + 1,  y2 = y1 + 1;
    x1 = min(max(x1, 0), 255); x2 = min(max(x2, 0), 255);
    y1 = min(max(y1, 0), 255); y2 = min(max(y2, 0), 255);
    const float* img = x + (long)b * 65536;
    const float p11 = img[y1 * 256 + x1];
    const float p12 = img[y2 * 256 + x1];
    const float p21 = img[y1 * 256 + x2];
    const float p22 = img[y2 * 256 + x2];
    const float wx1 = __fsub_rn((float)x2, px);
    const float wx2 = __fsub_rn(px, (float)x1);
    const float wy1 = __fsub_rn((float)y2, py);
    const float wy2 = __fsub_rn(py, (float)y1);
    const float sa = __fadd_rn(__fmul_rn(wy1, p11), __fmul_rn(wy2, p12));
    const float sb = __fadd_rn(__fmul_rn(wy1, p21), __fmul_rn(wy2, p22));
    const float r  = __fadd_rn(__fmul_rn(wx1, sa), __fmul_rn(wx2, sb));
    const float o  = __fadd_rn(__fmul_rn(r, ow[0]), ob[0]);
    out[idx] = 1.f / (1.f + expf(-o));
}

extern "C" void kernel_launch(void* const* d_in, const int* in_sizes, int n_in,
                              void* d_out, int out_size, void* d_ws, size_t ws_size,
                              hipStream_t stream)
{
    const float* x   = (const float*)d_in[0];
    const float* c1w = (const float*)d_in[1];
    const float* c1b = (const float*)d_in[2];
    const float* c2w = (const float*)d_in[3];
    const float* c2b = (const float*)d_in[4];
    const float* d1w = (const float*)d_in[5];
    const float* d1b = (const float*)d_in[6];
    const float* d2w = (const float*)d_in[7];
    const float* d2b = (const float*)d_in[8];
    const float* d3w = (const float*)d_in[9];
    const float* d3b = (const float*)d_in[10];
    const float* ow  = (const float*)d_in[11];
    const float* ob  = (const float*)d_in[12];

    char*  ws   = (char*)d_ws;
    float* th   = (float*)(ws + TH_OFF);
    float* h1   = (float*)(ws + H1_OFF);
    float* p1   = (float*)(ws + P1_OFF);
    float* part = (float*)(ws + PART_OFF);   // reuses p1 space (p1 dead)
    float* p2   = (float*)(ws + P2_OFF);

    k_c1    <<<dim3(8, 8, 128),   256, 0, stream>>>(x, c1w, c1b, p1);
    k_c2    <<<dim3(4, 16, 128),  256, 0, stream>>>(p1, c2w, c2b, p2);
    k_d1a   <<<dim3(311, 4),      256, 0, stream>>>(p2, d1w, part);
    k_d1b   <<<dim3(128),         128, 0, stream>>>(part, h1);
    k_head  <<<dim3(128),         128, 0, stream>>>(h1, d1b, d2w, d2b, d3w, d3b, th);
    k_sample<<<dim3(32768),       256, 0, stream>>>(x, th, ow, ob, (float*)d_out);
}

// Round 11
// 1033.492 us; speedup vs baseline: 2.7916x; 1.0098x over previous
//
#include <hip/hip_runtime.h>

// R19: two independent changes on top of R18 (PASSED, 1043.6us):
//  1) k_c2 v6: packed-FMA pairs. Adjacent oc accumulators {2j,2j+1} updated
//     via __builtin_elementwise_fma on float2 -> backend can select
//     v_pk_fma_f32 (VOP3P): one instruction = two independent IEEE FMAs.
//     Each accumulator's (ky,kx,ic)-sequential chain is unchanged ->
//     bit-exact. If the backend declines, it emits 2x v_fma == R18 exactly.
//     Mechanism: k_c2 is at 85% of the m07-measured v_fma issue ceiling
//     (103 TF); pk halves VALU issue slots per FMA.
//  2) k_d1b + k_head fused into k_d1bh (same block b, same chains, one
//     launch fewer, no h1 round-trip). Trivially bit-exact.
// NUMERICS CONTRACT (do not violate): golden is faithful float32 numpy;
// border-degenerate bilinear pixels flip discontinuously on ~1e-6 theta
// changes. Every conv/dense output must keep its exact sequential chain
// ((ky,kx) for conv1, (ky,kx,ic) for conv2, panel-k for dense1).
//
// ---- workspace (bytes), ~175MB ----
// th   f32[128*6]            @ 0
// h1   f32[128*120]          @ 4096   (unused since R19 fusion; kept)
// p1   f32 NHWC [128][126][126][14] @ 65536      (113,799,168 B)
// part f32[311][128][120]    @ 65536  (19,107,840 B; overlaps p1: p1 is dead
//                                      before k_d1a writes part)
// p2   f32[128][119072]      @ 113930240         (60,964,864 B)
#define TH_OFF   0ull
#define H1_OFF   4096ull
#define P1_OFF   65536ull
#define PART_OFF 65536ull
#define P2_OFF   113930240ull

typedef float v2f __attribute__((ext_vector_type(2)));

// ======= conv1 5x5 (1->14) + bias + relu + maxpool2, tiled (v2 == R18) ===
// block: 16x16 pool outputs, 1 batch; p1 NHWC [126][126][14]
// Weights/bias from GLOBAL at thread-independent (uniform) addresses ->
// SMEM s_load, zero LDS-pipe cost; LDS carries only the input tile.
__global__ __launch_bounds__(256) void k_c1(const float* __restrict__ x,
        const float* __restrict__ w1, const float* __restrict__ b1,
        float* __restrict__ p1)
{
    __shared__ float s_in[36*36];
    const int b   = blockIdx.z;
    const int ty0 = blockIdx.y * 16, tx0 = blockIdx.x * 16;
    const int tid = threadIdx.x;
    for (int i = tid; i < 36*36; i += 256) {
        int r = i / 36, c = i % 36;
        int gy = 2*ty0 + r, gx = 2*tx0 + c;
        float v = 0.f;
        if (gy < 256 && gx < 256) v = x[(long)(b*256 + gy)*256 + gx];
        s_in[i] = v;
    }
    __syncthreads();

    const int py = tid >> 4, px = tid & 15;
    float a0[14], a1[14], a2[14], a3[14];
    #pragma unroll
    for (int c = 0; c < 14; ++c) { a0[c]=0.f; a1[c]=0.f; a2[c]=0.f; a3[c]=0.f; }
    const int iy = 2*py, ix = 2*px;
    // chain order per accumulator: (ky,kx) sequential == R7
    #pragma unroll
    for (int ky = 0; ky < 5; ++ky) {
      #pragma unroll
      for (int kx = 0; kx < 5; ++kx) {
        float wv[14];
        #pragma unroll
        for (int c = 0; c < 14; ++c) wv[c] = w1[(ky*5+kx)*14 + c];  // uniform -> s_load
        const float* ip = &s_in[(iy+ky)*36 + ix + kx];
        float v00 = ip[0],  v01 = ip[1];
        float v10 = ip[36], v11 = ip[37];
        #pragma unroll
        for (int c = 0; c < 14; ++c) {
            a0[c] = fmaf(v00, wv[c], a0[c]);
            a1[c] = fmaf(v01, wv[c], a1[c]);
            a2[c] = fmaf(v10, wv[c], a2[c]);
            a3[c] = fmaf(v11, wv[c], a3[c]);
        }
      }
    }
    const int oy = ty0 + py, ox = tx0 + px;
    if (oy < 126 && ox < 126) {
        float* op = &p1[((long)(b*126 + oy)*126 + ox)*14];
        #pragma unroll
        for (int c = 0; c < 14; ++c) {
            float bb = b1[c];                       // uniform -> s_load
            // R7 pool order: (0,0),(0,1),(1,0),(1,1)
            float m = fmaxf(__fadd_rn(a0[c], bb), 0.f);
            m = fmaxf(m, fmaxf(__fadd_rn(a1[c], bb), 0.f));
            m = fmaxf(m, fmaxf(__fadd_rn(a2[c], bb), 0.f));
            m = fmaxf(m, fmaxf(__fadd_rn(a3[c], bb), 0.f));
            op[c] = m;
        }
    }
}

// ======= conv2 5x5 (14->32) + bias + relu + maxpool2 (v6: pk-FMA) ========
// block: 256 thr = 128 pos (8 conv rows x 16 col-pairs) x 2 oc-groups(16).
// LDS: s_in[12][14][38] = 25,536 B -> 6 blocks/CU; 8192 blocks.
// Weights: GLOBAL w2 at readfirstlane-uniform address -> scalar s_load.
// Accumulators packed in oc-pairs (v2f); __builtin_elementwise_fma gives
// the backend license to emit v_pk_fma_f32 (2 independent IEEE FMAs/instr).
// Per-accumulator (ky,kx,ic) chain order unchanged -> bit-exact vs R18.
#define C2_BLOCK(KX, VL, VR)                                        \
  { const int kb = (ky*5 + (KX))*14;                                \
    _Pragma("unroll")                                               \
    for (int ic = 0; ic < 14; ++ic) {                               \
      const float* wp = &w2[(kb + ic)*32 + ocb];                    \
      float4 wA = *reinterpret_cast<const float4*>(wp);             \
      float4 wB = *reinterpret_cast<const float4*>(wp + 4);         \
      float4 wC = *reinterpret_cast<const float4*>(wp + 8);         \
      float4 wD = *reinterpret_cast<const float4*>(wp + 12);        \
      v2f wq0 = {wA.x, wA.y}, wq1 = {wA.z, wA.w};                   \
      v2f wq2 = {wB.x, wB.y}, wq3 = {wB.z, wB.w};                   \
      v2f wq4 = {wC.x, wC.y}, wq5 = {wC.z, wC.w};                   \
      v2f wq6 = {wD.x, wD.y}, wq7 = {wD.z, wD.w};                   \
      v2f wq[8] = {wq0, wq1, wq2, wq3, wq4, wq5, wq6, wq7};         \
      float vl = (VL), vr = (VR);                                   \
      v2f vl2 = {vl, vl}, vr2 = {vr, vr};                           \
      _Pragma("unroll")                                             \
      for (int j = 0; j < 8; ++j) {                                 \
        accL2[j] = __builtin_elementwise_fma(vl2, wq[j], accL2[j]); \
        accR2[j] = __builtin_elementwise_fma(vr2, wq[j], accR2[j]); \
      } } }

__global__ __launch_bounds__(256) void k_c2(const float* __restrict__ p1,
        const float* __restrict__ w2, const float* __restrict__ b2,
        float* __restrict__ p2)
{
    __shared__ float s_in[12*14*38];     // 25,536 B  [r 0..11][ic][cc pad38]
    const int b   = blockIdx.z;
    const int ty0 = blockIdx.y * 4, tx0 = blockIdx.x * 16;   // pooled origin
    const int tid = threadIdx.x;

    // stage 12 input rows x 36 cols x 14 ic (conv rows 8*by .. +7 need
    // input rows 8*by .. +11)
    for (int i = tid; i < 12*36*14; i += 256) {
        int ic = i % 14, rem = i / 14;
        int cc = rem % 36, r = rem / 36;
        int gy = 2*ty0 + r, gx = 2*tx0 + cc;
        float v = 0.f;
        if (gy < 126 && gx < 126) v = p1[((long)(b*126 + gy)*126 + gx)*14 + ic];
        s_in[(r*14 + ic)*38 + cc] = v;
    }
    __syncthreads();

    // cg (tid bit 7) is uniform within each 64-lane wave; readfirstlane makes
    // that provable -> weight addresses become scalar (s_load path).
    const int cg  = __builtin_amdgcn_readfirstlane(tid >> 7);  // 0..1
    const int t   = tid & 127;
    const int py  = t >> 4;              // conv row in tile, 0..7
    const int ppx = t & 15;              // column pair, 0..15
    const int ocb = cg * 16;
    const int bx  = 2 * ppx;             // left conv col (even)

    v2f accL2[8], accR2[8];
    #pragma unroll
    for (int j = 0; j < 8; ++j) {
        accL2[j] = (v2f){0.f, 0.f};
        accR2[j] = (v2f){0.f, 0.f};
    }

    for (int ky = 0; ky < 5; ++ky) {
        const float* rp = &s_in[((py + ky)*14)*38 + bx];
        float2 X[14], Y[14];
        #pragma unroll
        for (int ic = 0; ic < 14; ++ic)
            X[ic] = *reinterpret_cast<const float2*>(rp + ic*38);      // cols bx,bx+1
        #pragma unroll
        for (int ic = 0; ic < 14; ++ic)
            Y[ic] = *reinterpret_cast<const float2*>(rp + ic*38 + 2);  // cols bx+2,bx+3
        C2_BLOCK(0, X[ic].x, X[ic].y)      // cols (bx+0, bx+1)
        C2_BLOCK(1, X[ic].y, Y[ic].x)      // cols (bx+1, bx+2)
        C2_BLOCK(2, Y[ic].x, Y[ic].y)      // cols (bx+2, bx+3)
        #pragma unroll
        for (int ic = 0; ic < 14; ++ic)
            X[ic] = *reinterpret_cast<const float2*>(rp + ic*38 + 4);  // cols bx+4,bx+5
        C2_BLOCK(3, Y[ic].y, X[ic].x)      // cols (bx+3, bx+4)
        C2_BLOCK(4, X[ic].x, X[ic].y)      // cols (bx+4, bx+5)
    }

    // pool: own row pair-of-cols + partner row (py^1 == lane^16, same wave).
    // R7 order (0,0),(0,1),(1,0),(1,1): max is order-invariant, bit-exact.
    const int prow = ty0 + (py >> 1);
    const int pcol = tx0 + ppx;
    const bool wr = ((py & 1) == 0) && prow < 61 && pcol < 61;
    float* op = &p2[(long)b*119072 + (long)(prow*61 + pcol)*32 + ocb];
    #pragma unroll
    for (int c = 0; c < 16; ++c) {
        float aL = accL2[c >> 1][c & 1];
        float aR = accR2[c >> 1][c & 1];
        float bb = b2[ocb + c];
        float m0 = fmaxf(__fadd_rn(aL, bb), 0.f);
        m0 = fmaxf(m0, fmaxf(__fadd_rn(aR, bb), 0.f));
        float m1 = __shfl_xor(m0, 16, 64);
        if (wr) op[c] = fmaxf(m0, m1);
    }
}

// ======= dense1 phase A: per-panel partials (bit-exact R7 panel chains) ====
// grid (311, 4), 256 thr: panel p, batch-group of 32 SPLIT across two waves
// (wave 0: b0..b0+15, wave 1: b0+16..b0+31). Same traffic as R13 (w reads
// shared via L1), 2x resident waves. thread = (half, column n).
// part[p][b][n] = sum_{k in panel p} p2[b][k]*w[k][n]  (sequential k FMA)
__global__ __launch_bounds__(256) void k_d1a(const float* __restrict__ p2,
        const float* __restrict__ w, float* __restrict__ part)
{
    const int n = threadIdx.x & 127;
    const int half = threadIdx.x >> 7;           // 0..1, wave-uniform
    const int panel = blockIdx.x;
    const int b0 = blockIdx.y * 32 + half * 16;
    if (n >= 120) return;
    const int kp = panel * 384;
    const int ke = (kp + 384 < 119072) ? kp + 384 : 119072;
    const float* a0 = p2 + (long)b0 * 119072;
    float p[16];
    #pragma unroll
    for (int i = 0; i < 16; ++i) p[i] = 0.f;
    for (int k = kp; k < ke; ++k) {
        float wv = w[(long)k * 120 + n];
        #pragma unroll
        for (int i = 0; i < 16; ++i)
            p[i] = fmaf(a0[(long)i * 119072 + k], wv, p[i]);
    }
    #pragma unroll
    for (int i = 0; i < 16; ++i)
        part[((long)panel * 128 + b0 + i) * 120 + n] = p[i];
}

// ======= dense1 phase B + head, fused (bit-exact R7 chains) =======
// One block per batch b, 128 threads. Phase B: in-order panel sum for
// column t (== k_d1b chain), then relu(h+d1b) into s1 (== k_head formula).
// Then d2+relu, d3+bias -> theta, all sequential-k FMA as before.
__global__ __launch_bounds__(128) void k_d1bh(const float* __restrict__ part,
        const float* __restrict__ d1bias, const float* __restrict__ d2w,
        const float* __restrict__ d2b, const float* __restrict__ d3w,
        const float* __restrict__ d3b, float* __restrict__ theta)
{
    __shared__ float s1[120], s2[84];
    const int b = blockIdx.x, t = threadIdx.x;
    if (t < 120) {
        float h = 0.f;
        for (int p = 0; p < 311; ++p)
            h = __fadd_rn(h, part[((long)p * 128 + b) * 120 + t]);
        s1[t] = fmaxf(__fadd_rn(h, d1bias[t]), 0.f);
    }
    __syncthreads();
    if (t < 84) {
        float a = 0.f;
        for (int k = 0; k < 120; ++k) a = fmaf(s1[k], d2w[k * 84 + t], a);
        s2[t] = fmaxf(__fadd_rn(a, d2b[t]), 0.f);
    }
    __syncthreads();
    if (t < 6) {
        float a = 0.f;
        for (int k = 0; k < 84; ++k) a = fmaf(s2[k], d3w[k * 6 + t], a);
        theta[b * 6 + t] = __fadd_rn(a, d3b[t]);
    }
}

// ======= sampler: strict f32 reference expression tree (== R7/R18) =======
// b is block-uniform (256-thr blocks never straddle a batch): computing it
// from blockIdx makes theta loads scalar s_load + image base SGPR-resident.
__global__ __launch_bounds__(256) void k_sample(const float* __restrict__ x,
        const float* __restrict__ theta, const float* __restrict__ ow,
        const float* __restrict__ ob, float* __restrict__ out)
{
    const int b   = blockIdx.x >> 8;                  // uniform
    const int pix = ((blockIdx.x & 255) << 8) | threadIdx.x;
    const int idx = (b << 16) | pix;
    const int yy  = pix >> 8, xx = pix & 255;
    const float gx = __fadd_rn((float)xx * (1.f / 128.f), -1.f);
    const float gy = __fadd_rn((float)yy * (1.f / 128.f), -1.f);
    const float* th = &theta[b * 6];
    float rx = __fmul_rn(th[0], gx);
    rx = fmaf(th[1], gy, rx);
    rx = __fadd_rn(rx, th[2]);
    float ry = __fmul_rn(th[3], gx);
    ry = fmaf(th[4], gy, ry);
    ry = __fadd_rn(ry, th[5]);
    const float px = __fmul_rn(__fmul_rn(__fadd_rn(rx, 1.f), 0.5f), 256.f);
    const float py = __fmul_rn(__fmul_rn(__fadd_rn(ry, 1.f), 0.5f), 256.f);
    int x1 = (int)floorf(px), y1 = (int)floorf(py);
    int x2 = x1 + 1,  y2 = y1 + 1;
    x1 = min(max(x1, 0), 255); x2 = min(max(x2, 0), 255);
    y1 = min(max(y1, 0), 255); y2 = min(max(y2, 0), 255);
    const float* img = x + (long)b * 65536;
    const float p11 = img[y1 * 256 + x1];
    const float p12 = img[y2 * 256 + x1];
    const float p21 = img[y1 * 256 + x2];
    const float p22 = img[y2 * 256 + x2];
    const float wx1 = __fsub_rn((float)x2, px);
    const float wx2 = __fsub_rn(px, (float)x1);
    const float wy1 = __fsub_rn((float)y2, py);
    const float wy2 = __fsub_rn(py, (float)y1);
    const float sa = __fadd_rn(__fmul_rn(wy1, p11), __fmul_rn(wy2, p12));
    const float sb = __fadd_rn(__fmul_rn(wy1, p21), __fmul_rn(wy2, p22));
    const float r  = __fadd_rn(__fmul_rn(wx1, sa), __fmul_rn(wx2, sb));
    const float o  = __fadd_rn(__fmul_rn(r, ow[0]), ob[0]);
    out[idx] = 1.f / (1.f + expf(-o));
}

extern "C" void kernel_launch(void* const* d_in, const int* in_sizes, int n_in,
                              void* d_out, int out_size, void* d_ws, size_t ws_size,
                              hipStream_t stream)
{
    const float* x   = (const float*)d_in[0];
    const float* c1w = (const float*)d_in[1];
    const float* c1b = (const float*)d_in[2];
    const float* c2w = (const float*)d_in[3];
    const float* c2b = (const float*)d_in[4];
    const float* d1w = (const float*)d_in[5];
    const float* d1b = (const float*)d_in[6];
    const float* d2w = (const float*)d_in[7];
    const float* d2b = (const float*)d_in[8];
    const float* d3w = (const float*)d_in[9];
    const float* d3b = (const float*)d_in[10];
    const float* ow  = (const float*)d_in[11];
    const float* ob  = (const float*)d_in[12];

    char*  ws   = (char*)d_ws;
    float* th   = (float*)(ws + TH_OFF);
    float* p1   = (float*)(ws + P1_OFF);
    float* part = (float*)(ws + PART_OFF);   // reuses p1 space (p1 dead)
    float* p2   = (float*)(ws + P2_OFF);

    k_c1    <<<dim3(8, 8, 128),   256, 0, stream>>>(x, c1w, c1b, p1);
    k_c2    <<<dim3(4, 16, 128),  256, 0, stream>>>(p1, c2w, c2b, p2);
    k_d1a   <<<dim3(311, 4),      256, 0, stream>>>(p2, d1w, part);
    k_d1bh  <<<dim3(128),         128, 0, stream>>>(part, d1b, d2w, d2b, d3w, d3b, th);
    k_sample<<<dim3(32768),       256, 0, stream>>>(x, th, ow, ob, (float*)d_out);
}